// Round 4
// baseline (77.942 us; speedup 1.0000x reference)
//
#include <hip/hip_runtime.h>
#include <hip/hip_bf16.h>
#include <cstddef>
#include <cstdint>

// T=128, B=8, E=1024, H=16, D=64. GEMMs 1024^3. fp16 operands (fp32->fp16
// conversion fused into GEMM staging), fp32 MFMA accumulate.

typedef _Float16 f16;
typedef __attribute__((ext_vector_type(8))) _Float16 f16x8;
typedef __attribute__((ext_vector_type(4))) float f32x4;

#define GLOBAL_TO_LDS(g, l) __builtin_amdgcn_global_load_lds( \
    (const __attribute__((address_space(1))) void*)(g),       \
    (__attribute__((address_space(3))) void*)(l), 16, 0, 0)

// ---------------------------------------------------------------------------
// MFMA GEMM tile: C[m][n] = sum_k A[m][k]*B[n][k], row stride 1024 elems.
// TM x TN tile, BK=64, 256 thr = 4 waves (2x2), wave tile (TM/2, TN/2).
// Swizzle: 16B slot ^= row&7, applied on the SOURCE side (global col for
// gload_lds / cvt loads) with LDS kept linear; mirrored on ds_read.
// CVTA/CVTB: operand arrives as f32 and is converted during reg-staging
// (saves the separate tof16 pass; rounding identical to the old path).
// ---------------------------------------------------------------------------
template <int TM, int TN, bool CVTA, bool CVTB, class Epi>
__device__ __forceinline__ void gemm_tile(const void* Av, const void* Bv,
                                          int kbeg, int kend, int m0, int n0,
                                          Epi epi)
{
    constexpr int AITS = TM / 32, BITS = TN / 32;   // 2048 elems per it
    constexpr int FM = TM / 32, FN = TN / 32;       // frags per wave
    __shared__ __attribute__((aligned(16))) f16 As[TM * 64];
    __shared__ __attribute__((aligned(16))) f16 Bs[TN * 64];
    const int tid = threadIdx.x;
    const int wave = tid >> 6, lane = tid & 63;
    const int wr = wave >> 1, wc = wave & 1;
    const int l16 = lane & 15, lk = lane >> 4;
    f32x4 acc[FM][FN] = {};

    for (int k0 = kbeg; k0 < kend; k0 += 64) {
#pragma unroll
        for (int it = 0; it < AITS; ++it) {
            const int ebase = it * 2048 + wave * 512;
            const int e = ebase + lane * 8;
            const int row = e >> 6, slot = (e >> 3) & 7;
            const int scol = (slot ^ (row & 7)) << 3;
            if constexpr (CVTA) {
                const float* s = (const float*)Av + (size_t)(m0 + row) * 1024 + k0 + scol;
                const float4 x = *(const float4*)s;
                const float4 y = *(const float4*)(s + 4);
                f16x8 o;
                o[0] = (f16)x.x; o[1] = (f16)x.y; o[2] = (f16)x.z; o[3] = (f16)x.w;
                o[4] = (f16)y.x; o[5] = (f16)y.y; o[6] = (f16)y.z; o[7] = (f16)y.w;
                *(f16x8*)(As + e) = o;
            } else {
                GLOBAL_TO_LDS((const f16*)Av + (size_t)(m0 + row) * 1024 + k0 + scol,
                              As + ebase);
            }
        }
#pragma unroll
        for (int it = 0; it < BITS; ++it) {
            const int ebase = it * 2048 + wave * 512;
            const int e = ebase + lane * 8;
            const int row = e >> 6, slot = (e >> 3) & 7;
            const int scol = (slot ^ (row & 7)) << 3;
            if constexpr (CVTB) {
                const float* s = (const float*)Bv + (size_t)(n0 + row) * 1024 + k0 + scol;
                const float4 x = *(const float4*)s;
                const float4 y = *(const float4*)(s + 4);
                f16x8 o;
                o[0] = (f16)x.x; o[1] = (f16)x.y; o[2] = (f16)x.z; o[3] = (f16)x.w;
                o[4] = (f16)y.x; o[5] = (f16)y.y; o[6] = (f16)y.z; o[7] = (f16)y.w;
                *(f16x8*)(Bs + e) = o;
            } else {
                GLOBAL_TO_LDS((const f16*)Bv + (size_t)(n0 + row) * 1024 + k0 + scol,
                              Bs + ebase);
            }
        }
        __syncthreads();
#pragma unroll
        for (int ksl = 0; ksl < 2; ++ksl) {
            const int s = ksl * 4 + lk;
            f16x8 af[FM], bg[FN];
#pragma unroll
            for (int mi = 0; mi < FM; ++mi) {
                const int r = wr * (TM / 2) + mi * 16 + l16;
                af[mi] = *(const f16x8*)(As + r * 64 + ((s ^ (r & 7)) << 3));
            }
#pragma unroll
            for (int ni = 0; ni < FN; ++ni) {
                const int r = wc * (TN / 2) + ni * 16 + l16;
                bg[ni] = *(const f16x8*)(Bs + r * 64 + ((s ^ (r & 7)) << 3));
            }
#pragma unroll
            for (int mi = 0; mi < FM; ++mi)
#pragma unroll
                for (int ni = 0; ni < FN; ++ni)
                    acc[mi][ni] = __builtin_amdgcn_mfma_f32_16x16x32_f16(
                        af[mi], bg[ni], acc[mi][ni], 0, 0, 0);
        }
        __syncthreads();
    }
#pragma unroll
    for (int mi = 0; mi < FM; ++mi)
#pragma unroll
        for (int ni = 0; ni < FN; ++ni)
#pragma unroll
            for (int r = 0; r < 4; ++r)
                epi(m0 + wr * (TM / 2) + mi * 16 + lk * 4 + r,
                    n0 + wc * (TN / 2) + ni * 16 + l16, acc[mi][ni][r]);
}

// Head-major f16 epilogue: dst[n=(row&7)*16+(col>>6)][t=row>>3][d=col&63].
// addvec (spk_emb row 0) folded in for Q -> stores new_q directly.
struct EpiHead {
    f16* dst; const float* addvec;
    __device__ void operator()(int row, int col, float v) const {
        const float x = addvec ? v + addvec[col] : v;
        const int b = row & 7, t = row >> 3, h = col >> 6, d = col & 63;
        dst[(size_t)(((b << 4) + h) * 128 + t) * 64 + d] = (f16)x;
    }
};
struct EpiF32 {
    float* dst;
    __device__ void operator()(int row, int col, float v) const {
        dst[(size_t)row * 1024 + col] = v;
    }
};

// 4 projections, 1D grid 512 (= 2 blocks/CU). XCD pairing: z = (bid&7)>>1 so
// each XCD pair works one weight (2 MB W + 2 MB A fits the 4 MB per-XCD L2).
__global__ __launch_bounds__(256) void proj4_kernel(
    const float* __restrict__ query, const float* __restrict__ rel_pe,
    const float* __restrict__ qw, const float* __restrict__ kw,
    const float* __restrict__ vw, const float* __restrict__ rw,
    const float* __restrict__ spk_emb,
    f16* __restrict__ Qh, f16* __restrict__ Kh,
    f16* __restrict__ Vh, f16* __restrict__ Rh)
{
    const int bid = blockIdx.x;
    const int z = (bid & 7) >> 1;
    const int w = ((bid >> 3) << 1) + (bid & 1);   // 0..127
    const int m0 = (w >> 3) << 6;                  // 16 M-tiles of 64
    const int n0 = (w & 7) << 7;                   // 8 N-tiles of 128
    const float* A = (z == 3) ? rel_pe : query;
    const float* W = (z == 0) ? qw : (z == 1) ? kw : (z == 2) ? vw : rw;
    f16* dst = (z == 0) ? Qh : (z == 1) ? Kh : (z == 2) ? Vh : Rh;
    EpiHead epi{dst, (z == 0) ? spk_emb : nullptr};
    gemm_tile<64, 128, true, true>(A, W, 0, 1024, m0, n0, epi);
}

// Out projection, split-K2, 1D grid 256. XCD grouping: kz = (bid&7)>>2 so each
// XCD reads one K-half of ATT + ow (2 MB, L2-resident). A=ATT f16 (gload_lds),
// B=ow f32 (cvt-staged).
__global__ __launch_bounds__(256) void out_kernel(
    const f16* __restrict__ ATT, const float* __restrict__ ow,
    float* __restrict__ P0, float* __restrict__ P1)
{
    const int bid = blockIdx.x;
    const int g = bid & 7;
    const int kz = g >> 2;
    const int w = ((bid >> 3) << 2) + (g & 3);     // 0..127
    const int m0 = (w >> 3) << 6;
    const int n0 = (w & 7) << 7;
    EpiF32 epi{kz ? P1 : P0};
    gemm_tile<64, 128, false, true>(ATT, ow, kz * 512, kz * 512 + 512, m0, n0, epi);
}

__global__ __launch_bounds__(256) void addreduce_kernel(
    const float* __restrict__ a, const float* __restrict__ b, float* __restrict__ o)
{
    const int i = (blockIdx.x * 256 + threadIdx.x) * 4;
    const float4 x = *(const float4*)(a + i);
    const float4 y = *(const float4*)(b + i);
    *(float4*)(o + i) = make_float4(x.x + y.x, x.y + y.y, x.z + y.z, x.w + y.w);
}

// ---------------------------------------------------------------------------
// MFMA attention (unchanged from round 3 — verified). Block = (n, half).
// QK^T: A=newQ(LDS), B=K(LDS). PV: A=P(per-wave LDS), B=V^T(LDS transpose).
// a2 = utt * (spk ? dot1 : dot0); a3 = c[127-i+j] (j<=i); masked score=1e-30.
// ---------------------------------------------------------------------------
__global__ __launch_bounds__(256) void attn_mfma_kernel(
    const f16* __restrict__ Qh, const f16* __restrict__ Kh,
    const f16* __restrict__ Vh, const f16* __restrict__ Rh,
    const float* __restrict__ spk_emb, const int* __restrict__ spk_mask,
    const float* __restrict__ utt_mask, f16* __restrict__ ATT)
{
    __shared__ __attribute__((aligned(16))) char smem[58880];
    f16* nq = (f16*)smem;                  // [64][64]  swz   8192B
    f16* kt = (f16*)(smem + 8192);         // [128][64] swz  16384B
    f16* vt = (f16*)(smem + 24576);        // [64][128] swz  16384B
    f16* vs = (f16*)(smem + 40960);        // [128][64] swz stage; reused as P
    float* cbuf = (float*)(smem + 57344);  // 128 f32
    float* dd   = (float*)(smem + 57856);  // dot0[64], dot1[64]
    float* sq   = (float*)(smem + 58368);  // sq0[64], sq1[64]

    const int bx = blockIdx.x, n = bx >> 1, half = bx & 1;
    const int b = n >> 4, h = n & 15, i0 = half << 6;
    const int tid = threadIdx.x, wave = tid >> 6, lane = tid & 63;
    const int l16 = lane & 15, lk = lane >> 4;
    const size_t hb = (size_t)n * (128 * 64);

    if (tid < 128)
        sq[tid] = spk_emb[(tid >> 6) * 1024 + (h << 6) + (tid & 63)];

#pragma unroll
    for (int it = 0; it < 2; ++it) {
        const int ebase = it * 2048 + wave * 512;
        const int e = ebase + lane * 8;
        const int row = e >> 6, slot = (e >> 3) & 7;
        const int scol = (slot ^ (row & 7)) << 3;
        GLOBAL_TO_LDS(Qh + hb + (size_t)(i0 + row) * 64 + scol, nq + ebase);
    }
#pragma unroll
    for (int it = 0; it < 4; ++it) {
        const int ebase = it * 2048 + wave * 512;
        const int e = ebase + lane * 8;
        const int row = e >> 6, slot = (e >> 3) & 7;
        const int scol = (slot ^ (row & 7)) << 3;
        GLOBAL_TO_LDS(Kh + hb + (size_t)row * 64 + scol, kt + ebase);
        GLOBAL_TO_LDS(Vh + hb + (size_t)row * 64 + scol, vs + ebase);
    }
    __syncthreads();

#pragma unroll
    for (int dc = 0; dc < 2; ++dc) {
        const int dchunk = wave * 2 + dc;
#pragma unroll
        for (int jg = 0; jg < 2; ++jg) {
            const int j = jg * 64 + lane;
            const f16x8 v = *(const f16x8*)(vs + j * 64 + ((dchunk ^ (j & 7)) << 3));
#pragma unroll
            for (int e = 0; e < 8; ++e) {
                const int d = dchunk * 8 + e;
                vt[d * 128 + ((((j >> 3) ^ (d & 7)) << 3) | (j & 7))] = v[e];
            }
        }
    }

    if (tid < 128) {
        const int j = tid;
        float s = 0.f;
#pragma unroll
        for (int c = 0; c < 8; ++c) {
            const f16x8 rv = *(const f16x8*)(Rh + hb + (size_t)j * 64 + c * 8);
#pragma unroll
            for (int e = 0; e < 8; ++e)
                s = fmaf((float)rv[e], sq[c * 8 + e], s);
        }
        cbuf[j] = s;
    } else if (tid < 192) {
        const int i = tid - 128;
        float s0 = 0.f, s1 = 0.f;
#pragma unroll
        for (int c = 0; c < 8; ++c) {
            const f16x8 qv = *(const f16x8*)(nq + i * 64 + ((c ^ (i & 7)) << 3));
#pragma unroll
            for (int e = 0; e < 8; ++e) {
                const float q = (float)qv[e];
                s0 = fmaf(q, sq[c * 8 + e], s0);
                s1 = fmaf(q, sq[64 + c * 8 + e], s1);
            }
        }
        dd[i] = s0; dd[64 + i] = s1;
    }
    __syncthreads();

    const int iw = wave * 16 + l16;
    f16x8 af[2];
#pragma unroll
    for (int ksl = 0; ksl < 2; ++ksl) {
        const int s = ksl * 4 + lk;
        af[ksl] = *(const f16x8*)(nq + iw * 64 + ((s ^ (iw & 7)) << 3));
    }
    f32x4 sacc[8] = {};
#pragma unroll
    for (int ksl = 0; ksl < 2; ++ksl) {
        const int s = ksl * 4 + lk;
#pragma unroll
        for (int ni = 0; ni < 8; ++ni) {
            const int j = ni * 16 + l16;
            const f16x8 bg = *(const f16x8*)(kt + j * 64 + ((s ^ (j & 7)) << 3));
            sacc[ni] = __builtin_amdgcn_mfma_f32_16x16x32_f16(af[ksl], bg, sacc[ni], 0, 0, 0);
        }
    }

    const int il0 = wave * 16 + lk * 4;
    float sc[8][4];
#pragma unroll
    for (int ni = 0; ni < 8; ++ni) {
        const int j = ni * 16 + l16;
#pragma unroll
        for (int r = 0; r < 4; ++r) {
            const int il = il0 + r, i = i0 + il;
            const float du = utt_mask[((size_t)n * 128 + i) * 128 + j];
            const int   sm = spk_mask[((size_t)b * 128 + i) * 128 + j];
            const float a2 = du * (sm ? dd[64 + il] : dd[il]);
            const float a3 = (j <= i) ? cbuf[127 - i + j] : 0.f;
            const float v = (sacc[ni][r] + a2 + a3) * 0.125f;
            sc[ni][r] = (j > i) ? 1e-30f : v;
        }
    }
    float inv[4];
    f16* ps = vs + wave * 2048;
#pragma unroll
    for (int r = 0; r < 4; ++r) {
        float m = sc[0][r];
#pragma unroll
        for (int ni = 1; ni < 8; ++ni) m = fmaxf(m, sc[ni][r]);
#pragma unroll
        for (int off = 8; off > 0; off >>= 1) m = fmaxf(m, __shfl_xor(m, off, 64));
        float ssum = 0.f;
#pragma unroll
        for (int ni = 0; ni < 8; ++ni) {
            const float e = __expf(sc[ni][r] - m);
            sc[ni][r] = e;
            ssum += e;
        }
#pragma unroll
        for (int off = 8; off > 0; off >>= 1) ssum += __shfl_xor(ssum, off, 64);
        inv[r] = 1.f / ssum;
    }
#pragma unroll
    for (int ni = 0; ni < 8; ++ni) {
        const int j = ni * 16 + l16;
#pragma unroll
        for (int r = 0; r < 4; ++r) {
            const int il = lk * 4 + r;
            ps[il * 128 + ((((j >> 3) ^ (il & 7)) << 3) | (j & 7))] = (f16)sc[ni][r];
        }
    }

    f16x8 pa[4];
#pragma unroll
    for (int ks = 0; ks < 4; ++ks) {
        const int slot = ks * 4 + lk;
        pa[ks] = *(const f16x8*)(ps + l16 * 128 + ((slot ^ (l16 & 7)) << 3));
    }
    f32x4 oacc[4] = {};
#pragma unroll
    for (int ks = 0; ks < 4; ++ks) {
        const int slot = ks * 4 + lk;
#pragma unroll
        for (int nd = 0; nd < 4; ++nd) {
            const int d = nd * 16 + l16;
            const f16x8 vb = *(const f16x8*)(vt + d * 128 + ((slot ^ (d & 7)) << 3));
            oacc[nd] = __builtin_amdgcn_mfma_f32_16x16x32_f16(pa[ks], vb, oacc[nd], 0, 0, 0);
        }
    }
#pragma unroll
    for (int nd = 0; nd < 4; ++nd)
#pragma unroll
        for (int r = 0; r < 4; ++r) {
            const int i = i0 + il0 + r;
            const int col = (h << 6) + nd * 16 + l16;
            ATT[(size_t)(i * 8 + b) * 1024 + col] = (f16)(oacc[nd][r] * inv[r]);
        }
}

// ---------------------------------------------------------------------------
extern "C" void kernel_launch(void* const* d_in, const int* in_sizes, int n_in,
                              void* d_out, int out_size, void* d_ws, size_t ws_size,
                              hipStream_t stream)
{
    (void)in_sizes; (void)n_in; (void)out_size; (void)ws_size;

    const float* query  = (const float*)d_in[0];
    // d_in[1] (key), d_in[2] (value) unused: reference derives k,v from query.
    const float* rel_pe = (const float*)d_in[3];
    // d_in[4] attn_mask: causal, reproduced analytically (j > i).
    const float* utt    = (const float*)d_in[5];
    const int*   spk    = (const int*)d_in[6];
    const float* qw     = (const float*)d_in[7];
    const float* kw     = (const float*)d_in[8];
    const float* vw     = (const float*)d_in[9];
    const float* rw     = (const float*)d_in[10];
    const float* spke   = (const float*)d_in[11];
    const float* ow     = (const float*)d_in[12];

    char* ws = (char*)d_ws;
    f16* Qh  = (f16*)(ws);                 // 2 MB each, head-major [n][t][d]
    f16* Kh  = (f16*)(ws + (2u  << 20));
    f16* Vh  = (f16*)(ws + (4u  << 20));
    f16* Rh  = (f16*)(ws + (6u  << 20));
    f16* ATT = (f16*)(ws + (8u  << 20));   // 2 MB, [t*8+b][e]
    float* P0 = (float*)(ws + (12u << 20)); // 4 MB
    float* P1 = (float*)(ws + (16u << 20)); // 4 MB

    proj4_kernel<<<dim3(512), 256, 0, stream>>>(query, rel_pe, qw, kw, vw, rw,
                                                spke, Qh, Kh, Vh, Rh);
    attn_mfma_kernel<<<dim3(256), 256, 0, stream>>>(Qh, Kh, Vh, Rh, spke, spk, utt, ATT);
    out_kernel<<<dim3(256), 256, 0, stream>>>(ATT, ow, P0, P1);
    addreduce_kernel<<<dim3(1024), 256, 0, stream>>>(P0, P1, (float*)d_out);
}

// Round 5
// 60.128 us; speedup vs baseline: 1.2963x; 1.2963x over previous
//
#include <hip/hip_runtime.h>
#include <hip/hip_bf16.h>
#include <cstddef>
#include <cstdint>

// T=128, B=8, E=1024, H=16, D=64. GEMMs 1024^3.
// Pipeline: tof16 (f32->f16, 7 segments) -> proj4 (MFMA, 2-phase dbuf) ->
// attn (MFMA) -> out (MFMA split-K2) -> addreduce.
// All GEMM staging via global_load_lds (fire-and-forget) on L3-resident f16.

typedef _Float16 f16;
typedef __attribute__((ext_vector_type(8))) _Float16 f16x8;
typedef __attribute__((ext_vector_type(4))) float f32x4;

#define GLOBAL_TO_LDS(g, l) __builtin_amdgcn_global_load_lds( \
    (const __attribute__((address_space(1))) void*)(g),       \
    (__attribute__((address_space(3))) void*)(l), 16, 0, 0)

// ---------------------------------------------------------------------------
// fp32 -> fp16: 7 segments of 1M elems (query, rel_pe, qw, kw, vw, rw, ow).
// ---------------------------------------------------------------------------
struct Ptr7 { const float* s[7]; };

__global__ __launch_bounds__(256) void tof16_kernel(Ptr7 p, f16* dbase)
{
    const float* s = p.s[blockIdx.y];
    f16* d = dbase + (size_t)blockIdx.y * (1u << 20);
    const int i = (blockIdx.x * 256 + threadIdx.x) * 8;
    const float4 a = *(const float4*)(s + i);
    const float4 b = *(const float4*)(s + i + 4);
    f16x8 o;
    o[0] = (f16)a.x; o[1] = (f16)a.y; o[2] = (f16)a.z; o[3] = (f16)a.w;
    o[4] = (f16)b.x; o[5] = (f16)b.y; o[6] = (f16)b.z; o[7] = (f16)b.w;
    *(f16x8*)(d + i) = o;
}

// ---------------------------------------------------------------------------
// 2-phase double-buffered MFMA GEMM tile (T3-minimum recipe):
//   prologue: STAGE(buf0); barrier;
//   loop:     STAGE(buf^1, k+64); ds_read+MFMA(buf); barrier; flip.
// Staging loads overlap the compute phase; one vmcnt(0)+barrier per K-step.
// C[m][n] = sum_k A[m][k]*B[n][k], row stride 1024. TM x TN, BK=64, 4 waves.
// Swizzle: 16B slot ^= row&7 on the pre-swizzled GLOBAL source, LDS linear,
// mirrored on ds_read (r3-verified conflict-free pattern).
// ---------------------------------------------------------------------------
template <int TM, int TN, class Epi>
__device__ __forceinline__ void gemm2ph(const f16* __restrict__ A,
                                        const f16* __restrict__ B,
                                        int kbeg, int kend, int m0, int n0,
                                        Epi epi)
{
    constexpr int AITS = TM / 32, BITS = TN / 32;
    constexpr int FM = TM / 32, FN = TN / 32;
    __shared__ __attribute__((aligned(16))) f16 As[2][TM * 64];
    __shared__ __attribute__((aligned(16))) f16 Bs[2][TN * 64];
    const int tid = threadIdx.x;
    const int wave = tid >> 6, lane = tid & 63;
    const int wr = wave >> 1, wc = wave & 1;
    const int l16 = lane & 15, lk = lane >> 4;
    f32x4 acc[FM][FN] = {};

    auto stage = [&](int buf, int k0) {
#pragma unroll
        for (int it = 0; it < AITS; ++it) {
            const int ebase = it * 2048 + wave * 512;
            const int e = ebase + lane * 8;
            const int row = e >> 6, slot = (e >> 3) & 7;
            const int scol = (slot ^ (row & 7)) << 3;
            GLOBAL_TO_LDS(A + (size_t)(m0 + row) * 1024 + k0 + scol, &As[buf][ebase]);
        }
#pragma unroll
        for (int it = 0; it < BITS; ++it) {
            const int ebase = it * 2048 + wave * 512;
            const int e = ebase + lane * 8;
            const int row = e >> 6, slot = (e >> 3) & 7;
            const int scol = (slot ^ (row & 7)) << 3;
            GLOBAL_TO_LDS(B + (size_t)(n0 + row) * 1024 + k0 + scol, &Bs[buf][ebase]);
        }
    };

    stage(0, kbeg);
    __syncthreads();
    int cur = 0;
    for (int k0 = kbeg; k0 < kend; k0 += 64) {
        if (k0 + 64 < kend) stage(cur ^ 1, k0 + 64);   // prefetch next K-step
#pragma unroll
        for (int ksl = 0; ksl < 2; ++ksl) {
            const int s = ksl * 4 + lk;
            f16x8 af[FM], bg[FN];
#pragma unroll
            for (int mi = 0; mi < FM; ++mi) {
                const int r = wr * (TM / 2) + mi * 16 + l16;
                af[mi] = *(const f16x8*)(&As[cur][r * 64 + ((s ^ (r & 7)) << 3)]);
            }
#pragma unroll
            for (int ni = 0; ni < FN; ++ni) {
                const int r = wc * (TN / 2) + ni * 16 + l16;
                bg[ni] = *(const f16x8*)(&Bs[cur][r * 64 + ((s ^ (r & 7)) << 3)]);
            }
#pragma unroll
            for (int mi = 0; mi < FM; ++mi)
#pragma unroll
                for (int ni = 0; ni < FN; ++ni)
                    acc[mi][ni] = __builtin_amdgcn_mfma_f32_16x16x32_f16(
                        af[mi], bg[ni], acc[mi][ni], 0, 0, 0);
        }
        __syncthreads();   // drains prefetch vmcnt + compute lgkm; flip safe
        cur ^= 1;
    }
#pragma unroll
    for (int mi = 0; mi < FM; ++mi)
#pragma unroll
        for (int ni = 0; ni < FN; ++ni)
#pragma unroll
            for (int r = 0; r < 4; ++r)
                epi(m0 + wr * (TM / 2) + mi * 16 + lk * 4 + r,
                    n0 + wc * (TN / 2) + ni * 16 + l16, acc[mi][ni][r]);
}

// Head-major f16 epilogue: dst[n=(row&7)*16+(col>>6)][t=row>>3][d=col&63].
// addvec (spk_emb row 0) folded in for Q -> stores new_q directly.
struct EpiHead {
    f16* dst; const float* addvec;
    __device__ void operator()(int row, int col, float v) const {
        const float x = addvec ? v + addvec[col] : v;
        const int b = row & 7, t = row >> 3, h = col >> 6, d = col & 63;
        dst[(size_t)(((b << 4) + h) * 128 + t) * 64 + d] = (f16)x;
    }
};
struct EpiF32 {
    float* dst;
    __device__ void operator()(int row, int col, float v) const {
        dst[(size_t)row * 1024 + col] = v;
    }
};

// 4 projections, grid 512 (2 blocks/CU). z = (bid&7)>>1: each XCD pair owns
// one weight (2 MB f16 W + 2 MB A stay L2-resident per XCD).
__global__ __launch_bounds__(256) void proj4_kernel(
    const f16* __restrict__ qf, const f16* __restrict__ rf,
    const f16* __restrict__ wbase, const float* __restrict__ spk_emb,
    f16* __restrict__ Qh, f16* __restrict__ Kh,
    f16* __restrict__ Vh, f16* __restrict__ Rh)
{
    const int bid = blockIdx.x;
    const int z = (bid & 7) >> 1;
    const int w = ((bid >> 3) << 1) + (bid & 1);   // 0..127
    const int m0 = (w >> 3) << 6;                  // 16 M-tiles of 64
    const int n0 = (w & 7) << 7;                   // 8 N-tiles of 128
    const f16* A = (z == 3) ? rf : qf;
    const f16* W = wbase + ((size_t)z << 20);
    f16* dst = (z == 0) ? Qh : (z == 1) ? Kh : (z == 2) ? Vh : Rh;
    EpiHead epi{dst, (z == 0) ? spk_emb : nullptr};
    gemm2ph<64, 128>(A, W, 0, 1024, m0, n0, epi);
}

// Out projection, split-K2, grid 256. kz = (bid&7)>>2: each XCD group reads
// one K-half of ATT + ow (L2-resident).
__global__ __launch_bounds__(256) void out_kernel(
    const f16* __restrict__ ATT, const f16* __restrict__ owf,
    float* __restrict__ P0, float* __restrict__ P1)
{
    const int bid = blockIdx.x;
    const int g = bid & 7;
    const int kz = g >> 2;
    const int w = ((bid >> 3) << 2) + (g & 3);     // 0..127
    const int m0 = (w >> 3) << 6;
    const int n0 = (w & 7) << 7;
    EpiF32 epi{kz ? P1 : P0};
    gemm2ph<64, 128>(ATT, owf, kz * 512, kz * 512 + 512, m0, n0, epi);
}

__global__ __launch_bounds__(256) void addreduce_kernel(
    const float* __restrict__ a, const float* __restrict__ b, float* __restrict__ o)
{
    const int i = (blockIdx.x * 256 + threadIdx.x) * 4;
    const float4 x = *(const float4*)(a + i);
    const float4 y = *(const float4*)(b + i);
    *(float4*)(o + i) = make_float4(x.x + y.x, x.y + y.y, x.z + y.z, x.w + y.w);
}

// ---------------------------------------------------------------------------
// MFMA attention (verified r3). Block = (n, half): 64 q-rows, 4 waves.
// QK^T: A=newQ(LDS), B=K(LDS). PV: A=P(per-wave LDS), B=V^T(LDS transpose).
// a2 = utt * (spk ? dot1 : dot0); a3 = c[127-i+j] (j<=i); masked score=1e-30.
// ---------------------------------------------------------------------------
__global__ __launch_bounds__(256) void attn_mfma_kernel(
    const f16* __restrict__ Qh, const f16* __restrict__ Kh,
    const f16* __restrict__ Vh, const f16* __restrict__ Rh,
    const float* __restrict__ spk_emb, const int* __restrict__ spk_mask,
    const float* __restrict__ utt_mask, f16* __restrict__ ATT)
{
    __shared__ __attribute__((aligned(16))) char smem[58880];
    f16* nq = (f16*)smem;                  // [64][64]  swz   8192B
    f16* kt = (f16*)(smem + 8192);         // [128][64] swz  16384B
    f16* vt = (f16*)(smem + 24576);        // [64][128] swz  16384B
    f16* vs = (f16*)(smem + 40960);        // [128][64] swz stage; reused as P
    float* cbuf = (float*)(smem + 57344);  // 128 f32
    float* dd   = (float*)(smem + 57856);  // dot0[64], dot1[64]
    float* sq   = (float*)(smem + 58368);  // sq0[64], sq1[64]

    const int bx = blockIdx.x, n = bx >> 1, half = bx & 1;
    const int b = n >> 4, h = n & 15, i0 = half << 6;
    const int tid = threadIdx.x, wave = tid >> 6, lane = tid & 63;
    const int l16 = lane & 15, lk = lane >> 4;
    const size_t hb = (size_t)n * (128 * 64);

    if (tid < 128)
        sq[tid] = spk_emb[(tid >> 6) * 1024 + (h << 6) + (tid & 63)];

#pragma unroll
    for (int it = 0; it < 2; ++it) {
        const int ebase = it * 2048 + wave * 512;
        const int e = ebase + lane * 8;
        const int row = e >> 6, slot = (e >> 3) & 7;
        const int scol = (slot ^ (row & 7)) << 3;
        GLOBAL_TO_LDS(Qh + hb + (size_t)(i0 + row) * 64 + scol, nq + ebase);
    }
#pragma unroll
    for (int it = 0; it < 4; ++it) {
        const int ebase = it * 2048 + wave * 512;
        const int e = ebase + lane * 8;
        const int row = e >> 6, slot = (e >> 3) & 7;
        const int scol = (slot ^ (row & 7)) << 3;
        GLOBAL_TO_LDS(Kh + hb + (size_t)row * 64 + scol, kt + ebase);
        GLOBAL_TO_LDS(Vh + hb + (size_t)row * 64 + scol, vs + ebase);
    }
    __syncthreads();

#pragma unroll
    for (int dc = 0; dc < 2; ++dc) {
        const int dchunk = wave * 2 + dc;
#pragma unroll
        for (int jg = 0; jg < 2; ++jg) {
            const int j = jg * 64 + lane;
            const f16x8 v = *(const f16x8*)(vs + j * 64 + ((dchunk ^ (j & 7)) << 3));
#pragma unroll
            for (int e = 0; e < 8; ++e) {
                const int d = dchunk * 8 + e;
                vt[d * 128 + ((((j >> 3) ^ (d & 7)) << 3) | (j & 7))] = v[e];
            }
        }
    }

    if (tid < 128) {
        const int j = tid;
        float s = 0.f;
#pragma unroll
        for (int c = 0; c < 8; ++c) {
            const f16x8 rv = *(const f16x8*)(Rh + hb + (size_t)j * 64 + c * 8);
#pragma unroll
            for (int e = 0; e < 8; ++e)
                s = fmaf((float)rv[e], sq[c * 8 + e], s);
        }
        cbuf[j] = s;
    } else if (tid < 192) {
        const int i = tid - 128;
        float s0 = 0.f, s1 = 0.f;
#pragma unroll
        for (int c = 0; c < 8; ++c) {
            const f16x8 qv = *(const f16x8*)(nq + i * 64 + ((c ^ (i & 7)) << 3));
#pragma unroll
            for (int e = 0; e < 8; ++e) {
                const float q = (float)qv[e];
                s0 = fmaf(q, sq[c * 8 + e], s0);
                s1 = fmaf(q, sq[64 + c * 8 + e], s1);
            }
        }
        dd[i] = s0; dd[64 + i] = s1;
    }
    __syncthreads();

    const int iw = wave * 16 + l16;
    f16x8 af[2];
#pragma unroll
    for (int ksl = 0; ksl < 2; ++ksl) {
        const int s = ksl * 4 + lk;
        af[ksl] = *(const f16x8*)(nq + iw * 64 + ((s ^ (iw & 7)) << 3));
    }
    f32x4 sacc[8] = {};
#pragma unroll
    for (int ksl = 0; ksl < 2; ++ksl) {
        const int s = ksl * 4 + lk;
#pragma unroll
        for (int ni = 0; ni < 8; ++ni) {
            const int j = ni * 16 + l16;
            const f16x8 bg = *(const f16x8*)(kt + j * 64 + ((s ^ (j & 7)) << 3));
            sacc[ni] = __builtin_amdgcn_mfma_f32_16x16x32_f16(af[ksl], bg, sacc[ni], 0, 0, 0);
        }
    }

    const int il0 = wave * 16 + lk * 4;
    float sc[8][4];
#pragma unroll
    for (int ni = 0; ni < 8; ++ni) {
        const int j = ni * 16 + l16;
#pragma unroll
        for (int r = 0; r < 4; ++r) {
            const int il = il0 + r, i = i0 + il;
            const float du = utt_mask[((size_t)n * 128 + i) * 128 + j];
            const int   sm = spk_mask[((size_t)b * 128 + i) * 128 + j];
            const float a2 = du * (sm ? dd[64 + il] : dd[il]);
            const float a3 = (j <= i) ? cbuf[127 - i + j] : 0.f;
            const float v = (sacc[ni][r] + a2 + a3) * 0.125f;
            sc[ni][r] = (j > i) ? 1e-30f : v;
        }
    }
    float inv[4];
    f16* ps = vs + wave * 2048;
#pragma unroll
    for (int r = 0; r < 4; ++r) {
        float m = sc[0][r];
#pragma unroll
        for (int ni = 1; ni < 8; ++ni) m = fmaxf(m, sc[ni][r]);
#pragma unroll
        for (int off = 8; off > 0; off >>= 1) m = fmaxf(m, __shfl_xor(m, off, 64));
        float ssum = 0.f;
#pragma unroll
        for (int ni = 0; ni < 8; ++ni) {
            const float e = __expf(sc[ni][r] - m);
            sc[ni][r] = e;
            ssum += e;
        }
#pragma unroll
        for (int off = 8; off > 0; off >>= 1) ssum += __shfl_xor(ssum, off, 64);
        inv[r] = 1.f / ssum;
    }
#pragma unroll
    for (int ni = 0; ni < 8; ++ni) {
        const int j = ni * 16 + l16;
#pragma unroll
        for (int r = 0; r < 4; ++r) {
            const int il = lk * 4 + r;
            ps[il * 128 + ((((j >> 3) ^ (il & 7)) << 3) | (j & 7))] = (f16)sc[ni][r];
        }
    }

    f16x8 pa[4];
#pragma unroll
    for (int ks = 0; ks < 4; ++ks) {
        const int slot = ks * 4 + lk;
        pa[ks] = *(const f16x8*)(ps + l16 * 128 + ((slot ^ (l16 & 7)) << 3));
    }
    f32x4 oacc[4] = {};
#pragma unroll
    for (int ks = 0; ks < 4; ++ks) {
        const int slot = ks * 4 + lk;
#pragma unroll
        for (int nd = 0; nd < 4; ++nd) {
            const int d = nd * 16 + l16;
            const f16x8 vb = *(const f16x8*)(vt + d * 128 + ((slot ^ (d & 7)) << 3));
            oacc[nd] = __builtin_amdgcn_mfma_f32_16x16x32_f16(pa[ks], vb, oacc[nd], 0, 0, 0);
        }
    }
#pragma unroll
    for (int nd = 0; nd < 4; ++nd)
#pragma unroll
        for (int r = 0; r < 4; ++r) {
            const int i = i0 + il0 + r;
            const int col = (h << 6) + nd * 16 + l16;
            ATT[(size_t)(i * 8 + b) * 1024 + col] = (f16)(oacc[nd][r] * inv[r]);
        }
}

// ---------------------------------------------------------------------------
extern "C" void kernel_launch(void* const* d_in, const int* in_sizes, int n_in,
                              void* d_out, int out_size, void* d_ws, size_t ws_size,
                              hipStream_t stream)
{
    (void)in_sizes; (void)n_in; (void)out_size; (void)ws_size;

    const float* query  = (const float*)d_in[0];
    // d_in[1] (key), d_in[2] (value) unused: reference derives k,v from query.
    const float* rel_pe = (const float*)d_in[3];
    // d_in[4] attn_mask: causal, reproduced analytically (j > i).
    const float* utt    = (const float*)d_in[5];
    const int*   spk    = (const int*)d_in[6];
    const float* qw     = (const float*)d_in[7];
    const float* kw     = (const float*)d_in[8];
    const float* vw     = (const float*)d_in[9];
    const float* rw     = (const float*)d_in[10];
    const float* spke   = (const float*)d_in[11];
    const float* ow     = (const float*)d_in[12];

    char* ws = (char*)d_ws;
    f16* Qh  = (f16*)(ws);                  // 2 MB each, head-major [n][t][d]
    f16* Kh  = (f16*)(ws + (2u  << 20));
    f16* Vh  = (f16*)(ws + (4u  << 20));
    f16* Rh  = (f16*)(ws + (6u  << 20));
    f16* ATT = (f16*)(ws + (8u  << 20));    // 2 MB, [t*8+b][e]
    f16* fb  = (f16*)(ws + (10u << 20));    // 7 x 2 MB f16 conversions
    float* P0 = (float*)(ws + (24u << 20)); // 4 MB
    float* P1 = (float*)(ws + (28u << 20)); // 4 MB

    f16* qf = fb;                  // query
    f16* rf = fb + (1u << 20);     // rel_pe
    f16* wb = fb + (2u << 20);     // qw,kw,vw,rw
    f16* ob = fb + (6u << 20);     // ow

    Ptr7 p7;
    p7.s[0] = query; p7.s[1] = rel_pe; p7.s[2] = qw; p7.s[3] = kw;
    p7.s[4] = vw; p7.s[5] = rw; p7.s[6] = ow;

    tof16_kernel<<<dim3(512, 7), 256, 0, stream>>>(p7, fb);
    proj4_kernel<<<dim3(512), 256, 0, stream>>>(qf, rf, wb, spke, Qh, Kh, Vh, Rh);
    attn_mfma_kernel<<<dim3(256), 256, 0, stream>>>(Qh, Kh, Vh, Rh, spke, spk, utt, ATT);
    out_kernel<<<dim3(256), 256, 0, stream>>>(ATT, ob, P0, P1);
    addreduce_kernel<<<dim3(1024), 256, 0, stream>>>(P0, P1, (float*)d_out);
}